// Round 3
// baseline (218.338 us; speedup 1.0000x reference)
//
#include <hip/hip_runtime.h>
#include <math.h>

// minGRU bidirectional scan — one WAVE per sequence, zero barriers, deep prefetch.
// x: [8, 512, 8192] fp32. out: [8, 256, 8192] fp32.
//   a_t = sigmoid(-gate_t); b_t = sigmoid(gate_t)*g(h_t); H_t = a_t*H_{t-1} + b_t
//   g(h) = h>=0 ? h+1 : exp(h)
// Per-lane local scan from zero + prefix products; true output recovered as
//   ov[j] = ov0[j] + st * pp[j]  where st = state entering this lane's run.
// Carry across sub-tiles via lane-63 broadcast (wave-local, no LDS/barrier).

#define SEQ_L 8192
#define PER_LANE 8
#define SUB (64 * PER_LANE)        // 512 elements per wave sub-tile
#define NSUB (SEQ_L / SUB)         // 16
#define DQ 4                       // prefetch queue depth (sub-tiles)

__global__ __launch_bounds__(64, 2) void mingru_scan_kernel(
    const float* __restrict__ x, float* __restrict__ out) {
    const int blk = blockIdx.x;          // 0..2047 — one wave per sequence
    const int dir = blk >> 10;           // 0 = forward, 1 = backward
    const int s   = blk & 1023;
    const int b   = s >> 7;              // batch 0..7
    const int c   = s & 127;             // channel 0..127
    const int lane = threadIdx.x;        // 0..63 (block == one wave)

    const float* __restrict__ hrow = x + (size_t)((b * 512) + (dir * 256) + c) * SEQ_L;
    const float* __restrict__ grow = hrow + (size_t)128 * SEQ_L;
    float* __restrict__ orow = out + (size_t)((b * 256) + (dir * 128) + c) * SEQ_L;

    // rolling register prefetch queue: DQ sub-tiles × 4 float4 each
    float4 qh0[DQ], qh1[DQ], qg0[DQ], qg1[DQ];

#pragma unroll
    for (int k = 0; k < DQ; ++k) {
        const int base = k * SUB + lane * PER_LANE;
        const int p = dir ? (SEQ_L - base - PER_LANE) : base;
        qh0[k] = *(const float4*)(hrow + p);
        qh1[k] = *(const float4*)(hrow + p + 4);
        qg0[k] = *(const float4*)(grow + p);
        qg1[k] = *(const float4*)(grow + p + 4);
    }

    float carry = 0.0f;

#pragma unroll
    for (int t = 0; t < NSUB; ++t) {
        const int slot = t & (DQ - 1);
        const float4 h0 = qh0[slot], h1 = qh1[slot];
        const float4 g0 = qg0[slot], g1 = qg1[slot];

        // refill this slot with sub-tile t+DQ (keeps 16 wave-loads in flight)
        if (t + DQ < NSUB) {
            const int nb = (t + DQ) * SUB + lane * PER_LANE;
            const int np = dir ? (SEQ_L - nb - PER_LANE) : nb;
            qh0[slot] = *(const float4*)(hrow + np);
            qh1[slot] = *(const float4*)(hrow + np + 4);
            qg0[slot] = *(const float4*)(grow + np);
            qg1[slot] = *(const float4*)(grow + np + 4);
        }

        // ---- unpack into scan order (block-uniform branch) ----
        float hv[PER_LANE], gv[PER_LANE];
        if (dir == 0) {
            hv[0]=h0.x; hv[1]=h0.y; hv[2]=h0.z; hv[3]=h0.w;
            hv[4]=h1.x; hv[5]=h1.y; hv[6]=h1.z; hv[7]=h1.w;
            gv[0]=g0.x; gv[1]=g0.y; gv[2]=g0.z; gv[3]=g0.w;
            gv[4]=g1.x; gv[5]=g1.y; gv[6]=g1.z; gv[7]=g1.w;
        } else {
            hv[0]=h1.w; hv[1]=h1.z; hv[2]=h1.y; hv[3]=h1.x;
            hv[4]=h0.w; hv[5]=h0.z; hv[6]=h0.y; hv[7]=h0.x;
            gv[0]=g1.w; gv[1]=g1.z; gv[2]=g1.y; gv[3]=g1.x;
            gv[4]=g0.w; gv[5]=g0.z; gv[6]=g0.y; gv[7]=g0.x;
        }

        // ---- coefficients + local scan from zero; keep (ov0, pp) ----
        float pp[PER_LANE], ov0[PER_LANE];
        float ca = 1.0f, cb = 0.0f;
#pragma unroll
        for (int j = 0; j < PER_LANE; ++j) {
            const float gt = gv[j];
            const float e  = __expf(-fabsf(gt));
            const float r  = 1.0f / (1.0f + e);
            const float sn = e * r;                   // sigmoid(-|gt|)
            const float z  = (gt >= 0.0f) ? r  : sn;  // sigmoid(gt)
            const float a  = (gt >= 0.0f) ? sn : r;   // sigmoid(-gt)
            const float hh = hv[j];
            const float gf = (hh >= 0.0f) ? (hh + 1.0f) : __expf(hh);
            const float bb = z * gf;
            cb = a * cb + bb;
            ca = a * ca;
            ov0[j] = cb;
            pp[j]  = ca;
        }

        // ---- inclusive wave scan of (a,b) pair composition ----
        float pa = ca, pb = cb;
#pragma unroll
        for (int d = 1; d < 64; d <<= 1) {
            const float oa = __shfl_up(pa, d);
            const float ob = __shfl_up(pb, d);
            if (lane >= d) {
                pb = pa * ob + pb;   // pre-update pa
                pa = pa * oa;
            }
        }

        // ---- state entering this lane: exclusive prefix applied to carry ----
        float ea = __shfl_up(pa, 1);
        float eb = __shfl_up(pb, 1);
        if (lane == 0) { ea = 1.0f; eb = 0.0f; }
        const float st = ea * carry + eb;

        // ---- outputs via correction (independent fmas) ----
        float ov[PER_LANE];
#pragma unroll
        for (int j = 0; j < PER_LANE; ++j) ov[j] = ov0[j] + st * pp[j];

        // ---- store (reversed for backward) ----
        const int base = t * SUB + lane * PER_LANE;
        if (dir == 0) {
            *(float4*)(orow + base)     = make_float4(ov[0], ov[1], ov[2], ov[3]);
            *(float4*)(orow + base + 4) = make_float4(ov[4], ov[5], ov[6], ov[7]);
        } else {
            const int p = SEQ_L - base - PER_LANE;
            *(float4*)(orow + p)     = make_float4(ov[7], ov[6], ov[5], ov[4]);
            *(float4*)(orow + p + 4) = make_float4(ov[3], ov[2], ov[1], ov[0]);
        }

        // ---- carry across sub-tiles: lane-63 inclusive aggregate ----
        const float ga = __shfl(pa, 63);
        const float gb = __shfl(pb, 63);
        carry = ga * carry + gb;
    }
}

extern "C" void kernel_launch(void* const* d_in, const int* in_sizes, int n_in,
                              void* d_out, int out_size, void* d_ws, size_t ws_size,
                              hipStream_t stream) {
    const float* x = (const float*)d_in[0];
    float* out = (float*)d_out;
    // 2048 single-wave blocks = 8 batch * 128 channels * 2 directions
    mingru_scan_kernel<<<2048, 64, 0, stream>>>(x, out);
}